// Round 1
// baseline (71.179 us; speedup 1.0000x reference)
//
#include <hip/hip_runtime.h>

// FlatPoolIco: icosahedral 7-neighbor hex pooling with chart stitching.
// Input  x: (B=64, R=6, C=5, H=128, W=256) f32
// Output  : (B=64, R=6, C=5, 64, 128) f32
//
// Derivation (see round-0 analysis):
//  out(h,w) = mean of 7 taps at unpadded (2h+dh, 2w+dw),
//   dh/dw in {(0,0),(1,0),(1,1),(0,1),(-1,0),(-1,-1),(0,-1)}.
//  Only padded row 0 (h==0) and padded col 0 (w==0) are reachable:
//   padded(0,pw): pw in [1,128]  -> x[rot,      (c+4)%5, 127, 127+pw]
//                 pw in [129,256]-> x[(rot+1)%6,(c+4)%5, 256-pw, 255]
//                 pw == 0        -> x[b,0,0,0,0]                (corner)
//   padded(ph,0): ph in [1,128]  -> x[(rot+5)%6,(c+4)%5, 127, 128-ph]
//  Input vertex mask is redundant (its pixels only feed masked outputs).
//  Output mask zeroes (63,0) and (0,127) per slab.

#define WW 256

__global__ __launch_bounds__(256) void flat_pool_ico(const float* __restrict__ x,
                                                     float* __restrict__ out) {
    int t = blockIdx.x * 256 + threadIdx.x;
    int lane = t & 31;          // 32 threads per output row (128 cols / 4 per thread)
    int rowid = t >> 5;
    int h = rowid & 63;
    int tmp = rowid >> 6;
    int c = tmp % 5; tmp /= 5;
    int rot = tmp % 6;
    int b = tmp / 6;
    int w0 = lane << 2;         // output col start: 0..124
    int cm = w0 << 1;           // input col base:   2*w0

    int slab = (b * 6 + rot) * 5 + c;
    const float* xs   = x + ((long)slab << 15);   // own slab (32768 floats)
    const float* rowm = xs + (h << 9);            // input row 2h   (h*512)
    const float* rowb = rowm + WW;                // input row 2h+1

    float mid[9];  // row 2h   cols 2w0-1 .. 2w0+7
    float top[8];  // row 2h-1 cols 2w0-1 .. 2w0+6   (or padded row 0, pw = 2w0+i)
    float bot[8];  // row 2h+1 cols 2w0   .. 2w0+7

    {
        float4 a0 = *(const float4*)(rowm + cm);
        float4 a1 = *(const float4*)(rowm + cm + 4);
        mid[1]=a0.x; mid[2]=a0.y; mid[3]=a0.z; mid[4]=a0.w;
        mid[5]=a1.x; mid[6]=a1.y; mid[7]=a1.z; mid[8]=a1.w;
        float4 b0 = *(const float4*)(rowb + cm);
        float4 b1 = *(const float4*)(rowb + cm + 4);
        bot[0]=b0.x; bot[1]=b0.y; bot[2]=b0.z; bot[3]=b0.w;
        bot[4]=b1.x; bot[5]=b1.y; bot[6]=b1.z; bot[7]=b1.w;
    }

    int cprev = (c + 4) % 5;

    // mid[0] = t6 of w=w0 (col 2w0-1, or padded col 0 when lane==0)
    if (lane == 0) {
        const float* xn3 = x + ((long)((b * 6 + (rot + 5) % 6) * 5 + cprev) << 15) + 127 * WW;
        mid[0] = xn3[127 - (h << 1)];          // padded(1+2h, 0)
    } else {
        mid[0] = rowm[cm - 1];
    }

    if (h == 0) {
        // padded row 0: top[i] = padded(0, 2w0+i)
        const float* xn1 = x + ((long)((b * 6 + rot) * 5 + cprev) << 15) + 127 * WW + 127;
        const float* xn2 = x + ((long)((b * 6 + (rot + 1) % 6) * 5 + cprev) << 15) + 255;
        #pragma unroll
        for (int i = 0; i < 8; ++i) {
            int pw = cm + i;
            float v;
            if (pw == 0)        v = x[(long)b * 983040];       // corner -> flat idx 0
            else if (pw <= 128) v = xn1[pw];                    // nbr chart row 127
            else                v = xn2[(256 - pw) << 8];       // nbr rot col 255
            top[i] = v;
        }
    } else {
        const float* rowt = rowm - WW;         // input row 2h-1
        float4 t0v = *(const float4*)(rowt + cm);
        float4 t1v = *(const float4*)(rowt + cm + 4);
        top[1]=t0v.x; top[2]=t0v.y; top[3]=t0v.z; top[4]=t0v.w;
        top[5]=t1v.x; top[6]=t1v.y; top[7]=t1v.z;
        if (lane == 0) {
            const float* xn3 = x + ((long)((b * 6 + (rot + 5) % 6) * 5 + cprev) << 15) + 127 * WW;
            top[0] = xn3[128 - (h << 1)];      // padded(2h, 0)
        } else {
            top[0] = rowt[cm - 1];
        }
    }

    const float inv7 = 1.0f / 7.0f;
    float o[4];
    #pragma unroll
    for (int k = 0; k < 4; ++k) {
        float s = mid[2*k] + mid[2*k+1] + mid[2*k+2]
                + top[2*k] + top[2*k+1]
                + bot[2*k] + bot[2*k+1];
        o[k] = s * inv7;
    }

    // output vertex mask: (63,0) and (0,127)
    if (h == 63 && lane == 0)  o[0] = 0.0f;
    if (h == 0  && lane == 31) o[3] = 0.0f;

    float* op = out + ((long)slab << 13) + (h << 7) + w0;
    *(float4*)op = make_float4(o[0], o[1], o[2], o[3]);
}

extern "C" void kernel_launch(void* const* d_in, const int* in_sizes, int n_in,
                              void* d_out, int out_size, void* d_ws, size_t ws_size,
                              hipStream_t stream) {
    const float* x = (const float*)d_in[0];
    float* out = (float*)d_out;
    // total outputs = 64*6*5*64*128 = 15,728,640 ; 4 per thread ; 256 per block
    flat_pool_ico<<<15360, 256, 0, stream>>>(x, out);
}

// Round 3
// 59.144 us; speedup vs baseline: 1.2035x; 1.2035x over previous
//
#include <hip/hip_runtime.h>

// FlatPoolIco: icosahedral 7-neighbor hex pooling with chart stitching.
// Input  x: (B=64, R=6, C=5, H=128, W=256) f32
// Output  : (B=64, R=6, C=5, 64, 128) f32
//
// out(h,w) = mean of 7 taps:
//   row 2h-1: cols {2w-1, 2w}          (padded row 0 when h==0)
//   row 2h  : cols {2w-1, 2w, 2w+1}
//   row 2h+1: cols {2w, 2w+1}
// Boundary stitches (only padded row 0 / col 0 reachable):
//   padded(0,pw): pw==0        -> x[b,0,0,0,0]
//                 pw in [1,128]  -> x[rot,      (c+4)%5, 127, 127+pw]
//                 pw in [129,256]-> x[(rot+1)%6,(c+4)%5, 256-pw, 255]
//   padded(ph,0): ph in [1,128]  -> x[(rot+5)%6,(c+4)%5, 127, 128-ph]
// Input vertex mask is redundant; output mask zeroes (63,0),(0,127)/slab.
//
// v2: 8 outputs/thread (16 lanes per output row), left edge via __shfl_up,
//     nontemporal stores (via native ext_vector_type for the builtin).

#define WW 256

typedef float vfloat4 __attribute__((ext_vector_type(4)));

__global__ __launch_bounds__(256) void flat_pool_ico(const float* __restrict__ x,
                                                     float* __restrict__ out) {
    int t = blockIdx.x * 256 + threadIdx.x;
    int lane = t & 15;           // 16 threads per output row
    int rowid = t >> 4;
    int h = rowid & 63;
    int tmp = rowid >> 6;
    int c = tmp % 5; tmp /= 5;
    int rot = tmp % 6;
    int b = tmp / 6;
    int w0 = lane << 3;          // output col start: 0..120
    int cm = w0 << 1;            // input col base:   16*lane

    long slab = (long)((b * 6 + rot) * 5 + c);
    const float* xs   = x + (slab << 15);     // own slab (32768 floats)
    const float* rowm = xs + (h << 9);        // input row 2h
    const float* rowb = rowm + WW;            // input row 2h+1

    // M[j] = row 2h   col cm+j-1   (j=0..16)
    // T[j] = row 2h-1 col cm+j-1,  or padded(0, cm+j) when h==0  (j=0..15)
    // B[j] = row 2h+1 col cm+j     (j=0..15)
    float M[17], T[16], B[16];

    {
        vfloat4 a0 = *(const vfloat4*)(rowm + cm);
        vfloat4 a1 = *(const vfloat4*)(rowm + cm + 4);
        vfloat4 a2 = *(const vfloat4*)(rowm + cm + 8);
        vfloat4 a3 = *(const vfloat4*)(rowm + cm + 12);
        M[1]=a0.x;  M[2]=a0.y;  M[3]=a0.z;  M[4]=a0.w;
        M[5]=a1.x;  M[6]=a1.y;  M[7]=a1.z;  M[8]=a1.w;
        M[9]=a2.x;  M[10]=a2.y; M[11]=a2.z; M[12]=a2.w;
        M[13]=a3.x; M[14]=a3.y; M[15]=a3.z; M[16]=a3.w;
        vfloat4 c0 = *(const vfloat4*)(rowb + cm);
        vfloat4 c1 = *(const vfloat4*)(rowb + cm + 4);
        vfloat4 c2 = *(const vfloat4*)(rowb + cm + 8);
        vfloat4 c3 = *(const vfloat4*)(rowb + cm + 12);
        B[0]=c0.x;  B[1]=c0.y;  B[2]=c0.z;  B[3]=c0.w;
        B[4]=c1.x;  B[5]=c1.y;  B[6]=c1.z;  B[7]=c1.w;
        B[8]=c2.x;  B[9]=c2.y;  B[10]=c2.z; B[11]=c2.w;
        B[12]=c3.x; B[13]=c3.y; B[14]=c3.z; B[15]=c3.w;
    }

    int cprev = (c + 4) % 5;
    const float* xn3 = x + ((long)((b * 6 + (rot + 5) % 6) * 5 + cprev) << 15) + 127 * WW;

    // left edge of mid row: col cm-1 (prev lane's M[16]); lane 0 stitched
    {
        float midL = __shfl_up(M[16], 1);
        if (lane == 0) midL = xn3[127 - (h << 1)];   // padded(1+2h, 0)
        M[0] = midL;
    }

    if (h == 0) {
        // padded row 0: T[i] = padded(0, cm+i)
        const float* xn1 = x + ((long)((b * 6 + rot) * 5 + cprev) << 15) + 127 * WW + 127;
        const float* xn2 = x + ((long)((b * 6 + (rot + 1) % 6) * 5 + cprev) << 15) + 255;
        #pragma unroll
        for (int i = 0; i < 16; ++i) {
            int pw = cm + i;
            float v;
            if (pw == 0)        v = x[(long)b * 983040];   // corner -> flat idx 0
            else if (pw <= 128) v = xn1[pw];               // nbr chart row 127
            else                v = xn2[(256 - pw) << 8];  // nbr rot col 255
            T[i] = v;
        }
    } else {
        const float* rowt = rowm - WW;        // input row 2h-1
        vfloat4 t0 = *(const vfloat4*)(rowt + cm);
        vfloat4 t1 = *(const vfloat4*)(rowt + cm + 4);
        vfloat4 t2 = *(const vfloat4*)(rowt + cm + 8);
        vfloat4 t3 = *(const vfloat4*)(rowt + cm + 12);
        T[1]=t0.x;  T[2]=t0.y;  T[3]=t0.z;  T[4]=t0.w;
        T[5]=t1.x;  T[6]=t1.y;  T[7]=t1.z;  T[8]=t1.w;
        T[9]=t2.x;  T[10]=t2.y; T[11]=t2.z; T[12]=t2.w;
        T[13]=t3.x; T[14]=t3.y; T[15]=t3.z;
        float topL = __shfl_up(t3.w, 1);      // prev lane's col cm-1
        if (lane == 0) topL = xn3[128 - (h << 1)];   // padded(2h, 0)
        T[0] = topL;
    }

    const float inv7 = 1.0f / 7.0f;
    float o[8];
    #pragma unroll
    for (int k = 0; k < 8; ++k) {
        float s = M[2*k] + M[2*k+1] + M[2*k+2]
                + T[2*k] + T[2*k+1]
                + B[2*k] + B[2*k+1];
        o[k] = s * inv7;
    }

    // output vertex mask: (63,0) and (0,127)
    if (h == 63 && lane == 0)  o[0] = 0.0f;
    if (h == 0  && lane == 15) o[7] = 0.0f;

    float* op = out + (slab << 13) + (h << 7) + w0;
    vfloat4 s0 = { o[0], o[1], o[2], o[3] };
    vfloat4 s1 = { o[4], o[5], o[6], o[7] };
    __builtin_nontemporal_store(s0, (vfloat4*)op);
    __builtin_nontemporal_store(s1, (vfloat4*)(op + 4));
}

extern "C" void kernel_launch(void* const* d_in, const int* in_sizes, int n_in,
                              void* d_out, int out_size, void* d_ws, size_t ws_size,
                              hipStream_t stream) {
    const float* x = (const float*)d_in[0];
    float* out = (float*)d_out;
    // threads = 64*6*5*64*16 = 1,966,080 ; 256/block -> 7680 blocks
    flat_pool_ico<<<7680, 256, 0, stream>>>(x, out);
}